// Round 9
// baseline (15906.027 us; speedup 1.0000x reference)
//
#include <hip/hip_runtime.h>
#include <math.h>

// Problem constants
#define DD   512
#define LSEQ 2048
#define NBAT 16
#define RTOT (NBAT * LSEQ)   // 32768 rows

typedef __attribute__((ext_vector_type(8))) short bf16x8;
typedef __attribute__((ext_vector_type(4))) short s16x4;
typedef __attribute__((ext_vector_type(4))) float f32x4;

#define AS1(p) ((const __attribute__((address_space(1))) void*)(p))
#define AS3(p) ((__attribute__((address_space(3))) void*)(p))
#define MFMA16 __builtin_amdgcn_mfma_f32_16x16x32_bf16

__device__ __forceinline__ unsigned short f2bf(float f) {
  unsigned u = __builtin_bit_cast(unsigned, f);
  u += 0x7fffu + ((u >> 16) & 1u);
  return (unsigned short)(u >> 16);
}

// h LDS swizzle: element (m,n) at short-index m*512 + (n ^ ((m&7)<<3))
// b128 reads: even 8 words/bank; b16 writes: ~2-way (free).
#define SWZH(m, n) ((m) * 512u + ((n) ^ (((m) & 7u) << 3)))

// ---------------------------------------------------------------------------
// prep: fold BN into Wx (Wx' = Wx*diag(inv), b' = Wx(beta-mean*iv)+b_rnn),
// convert Wffn and Wh to bf16.
// blocks 0..511: Wx'+b' ; 512..1535: Wffn ; 1536..2047: Wh.
// ---------------------------------------------------------------------------
__global__ __launch_bounds__(256) void prep_kernel(
    const float* __restrict__ Wx, const float* __restrict__ gamma,
    const float* __restrict__ beta, const float* __restrict__ mean,
    const float* __restrict__ var, const float* __restrict__ brnn,
    const float* __restrict__ Wffn, const float* __restrict__ Wh,
    unsigned short* __restrict__ Wxp, unsigned short* __restrict__ Wfb,
    unsigned short* __restrict__ Whb, float* __restrict__ bprime)
{
  const unsigned tid = threadIdx.x, bx = blockIdx.x;
  if (bx < 512) {
    __shared__ float red[256];
    float partial = 0.f;
#pragma unroll
    for (int i = 0; i < 2; ++i) {
      unsigned d = i * 256u + tid;
      float iv = gamma[d] * rsqrtf(var[d] + 1e-5f);
      float w  = Wx[bx * 512u + d];
      Wxp[bx * 512u + d] = (unsigned short)f2bf(w * iv);
      partial += w * (beta[d] - mean[d] * iv);
    }
    red[tid] = partial; __syncthreads();
    for (unsigned s = 128; s > 0; s >>= 1) {
      if (tid < s) red[tid] += red[tid + s];
      __syncthreads();
    }
    if (tid == 0) bprime[bx] = red[0] + brnn[bx];
  } else if (bx < 1536) {
    unsigned row = bx - 512;
#pragma unroll
    for (int i = 0; i < 2; ++i) {
      unsigned d = i * 256u + tid;
      Wfb[row * 512u + d] = (unsigned short)f2bf(Wffn[row * 512u + d]);
    }
  } else {
    unsigned row = bx - 1536;
#pragma unroll
    for (int i = 0; i < 2; ++i) {
      unsigned d = i * 256u + tid;
      Whb[row * 512u + d] = (unsigned short)f2bf(Wh[row * 512u + d]);
    }
  }
}

// ---------------------------------------------------------------------------
// convert x (fp32) -> bf16, row-major (RTOT, D)
// ---------------------------------------------------------------------------
__global__ __launch_bounds__(256) void convx_kernel(
    const float* __restrict__ x, unsigned short* __restrict__ Xbf)
{
  const unsigned total4 = RTOT * DD / 4;
  unsigned i = blockIdx.x * 256u + threadIdx.x;
  const unsigned stride = gridDim.x * 256u;
  const float4* __restrict__ x4 = (const float4*)x;
  for (; i < total4; i += stride) {
    float4 v = x4[i];
    unsigned short o0 = f2bf(v.x), o1 = f2bf(v.y), o2 = f2bf(v.z), o3 = f2bf(v.w);
    unsigned long long pack = (unsigned long long)o0 |
                              ((unsigned long long)o1 << 16) |
                              ((unsigned long long)o2 << 32) |
                              ((unsigned long long)o3 << 48);
    *(unsigned long long*)(Xbf + i * 4u) = pack;
  }
}

// ---------------------------------------------------------------------------
// GEMM1: Ubf[t][n][m] = bf16( sum_d Xbf[r,d]*Wxp[n,d] + b'[n] ), r = m*L + t.
// [t][n][m] layout => rnn_rec's per-step u prefetch is 4 x 8B loads.
// ---------------------------------------------------------------------------
__global__ __launch_bounds__(256) void gemm_u_kernel(
    const unsigned short* __restrict__ A, const unsigned short* __restrict__ Bw,
    const float* __restrict__ bias, unsigned short* __restrict__ Ubf)
{
  __shared__ __align__(16) unsigned char lds[16384]; // A 8KB | B 8KB
  const unsigned tid = threadIdx.x;
  const unsigned lid = tid & 63u, wid = tid >> 6;
  const unsigned wr = wid >> 1, wc = wid & 1u;
  const unsigned rbase = blockIdx.x * 128u, nbase = blockIdx.y * 128u;

  f32x4 acc[4][4] = {};
  for (int kt = 0; kt < 16; ++kt) {
    __syncthreads();
#pragma unroll
    for (int i = 0; i < 2; ++i) {
      unsigned c = i * 256u + tid;
      const unsigned short* g = A + (rbase + (c >> 2)) * 512u + kt * 32u + (c & 3u) * 8u;
      __builtin_amdgcn_global_load_lds(AS1(g), AS3(lds + c * 16u), 16, 0, 0);
    }
#pragma unroll
    for (int i = 0; i < 2; ++i) {
      unsigned c = i * 256u + tid;
      const unsigned short* g = Bw + (nbase + (c >> 2)) * 512u + kt * 32u + (c & 3u) * 8u;
      __builtin_amdgcn_global_load_lds(AS1(g), AS3(lds + 8192u + c * 16u), 16, 0, 0);
    }
    __syncthreads();
    bf16x8 af[4], bfr[4];
#pragma unroll
    for (int mi = 0; mi < 4; ++mi)
      af[mi] = *(const bf16x8*)(lds + (wr * 64u + mi * 16u + (lid & 15u)) * 64u + (lid >> 4) * 16u);
#pragma unroll
    for (int ni = 0; ni < 4; ++ni)
      bfr[ni] = *(const bf16x8*)(lds + 8192u + (wc * 64u + ni * 16u + (lid & 15u)) * 64u + (lid >> 4) * 16u);
#pragma unroll
    for (int mi = 0; mi < 4; ++mi)
#pragma unroll
      for (int ni = 0; ni < 4; ++ni)
        acc[mi][ni] = MFMA16(af[mi], bfr[ni], acc[mi][ni], 0, 0, 0);
  }
#pragma unroll
  for (int mi = 0; mi < 4; ++mi)
#pragma unroll
    for (int ni = 0; ni < 4; ++ni) {
      unsigned e = nbase + wc * 64u + ni * 16u + (lid & 15u);
      float bb = bias[e];
#pragma unroll
      for (int j = 0; j < 4; ++j) {
        unsigned r = rbase + wr * 64u + mi * 16u + (lid >> 4) * 4u + j;
        unsigned t = r & 2047u, b = r >> 11u;
        Ubf[(t * 512u + e) * 16u + b] = f2bf(acc[mi][ni][j] + bb);
      }
    }
}

// ---------------------------------------------------------------------------
// Recurrence, SINGLE-CU v3. 1 WG x 512 thr (8 waves, 2/EU pinned via amdgpu
// attributes => 256-reg cap; arch budget ~235 w/ slack). Wave w owns 64 cols.
// Wh 16 k-chunks: 0..9  VGPR-stationary (160 regs/lane)
//                 10..12 LDS-resident ([c][n][32] chunk-major, even banks)
//                 13..15 streamed from L2 (48 staging regs, ~1-step lookahead,
//                        same addrs every step -> pure L2 hits)
// h: 2x16KB LDS dbuf (SWZH). u: bf16 [t][n][m], prefetched 1 step ahead.
// Per-step barrier = lgkmcnt(0)+s_barrier only (vmem rides across steps).
// Design pole: LDS BW ~240KB/step @ ~128B/cy ~= 1900 cy/step.
// ---------------------------------------------------------------------------
__global__ __attribute__((amdgpu_flat_work_group_size(512, 512),
                          amdgpu_waves_per_eu(2, 2)))
void rnn_rec_kernel(
    const unsigned short* __restrict__ Whb,
    const unsigned short* __restrict__ Ubf,
    unsigned short* __restrict__ Hs)
{
  __shared__ unsigned short hbuf[2][8192];   // 32 KB
  __shared__ unsigned short whs[49152];      // 96 KB: chunks 10..12, [c][n][32]

  const unsigned tid = threadIdx.x, lid = tid & 63u, w = tid >> 6;
  const unsigned mq = lid >> 4, ln = lid & 15u;   // mq = k-subgroup / m-group
  const unsigned nb = w * 64u;

  // h0 = 0
  for (unsigned i = tid; i < 8192u; i += 512u) hbuf[0][i] = 0;
  // stage Wh chunks 10..12 into whs, linear dst, b128 copies
  for (unsigned i = tid; i < 6144u; i += 512u) {
    unsigned s = i * 8u;
    unsigned c = s >> 14, r = s & 16383u;
    unsigned n = r >> 5, kk = r & 31u;
    *(bf16x8*)(whs + s) = *(const bf16x8*)(Whb + n * 512u + (10u + c) * 32u + kk);
  }

  // stationary B fragments: chunks 0..9 (k < 320) -> 160 VGPRs
  bf16x8 bo[10][4];
#pragma unroll
  for (int c = 0; c < 10; ++c)
#pragma unroll
    for (int nt = 0; nt < 4; ++nt)
      bo[c][nt] = *(const bf16x8*)(Whb + (nb + nt * 16u + ln) * 512u + (unsigned)c * 32u + mq * 8u);

  // u for step 1 (t=0): [t][n][m] -> 8B loads
  s16x4 uu[4];
#pragma unroll
  for (int nt = 0; nt < 4; ++nt)
    uu[nt] = *(const s16x4*)(Ubf + (0u * 512u + nb + nt * 16u + ln) * 16u + mq * 4u);

  // preheader: stream chunks 13,14,15 (k 416..512) for step 1
  bf16x8 bsA[4], bsB[4], bsC[4];
#pragma unroll
  for (int nt = 0; nt < 4; ++nt) {
    const unsigned short* base = Whb + (nb + nt * 16u + ln) * 512u + mq * 8u;
    bsA[nt] = *(const bf16x8*)(base + 416u);
    bsB[nt] = *(const bf16x8*)(base + 448u);
    bsC[nt] = *(const bf16x8*)(base + 480u);
  }

  __syncthreads();

  unsigned cur = 0;
  for (unsigned st = 1; st <= (unsigned)LSEQ; ++st) {
    const unsigned short* hb = hbuf[cur];
    unsigned short* hn = hbuf[cur ^ 1u];
    f32x4 acc[4] = {};

    // streamed chunks 13..15 (staged with ~full-step lookahead)
    {
      bf16x8 a = *(const bf16x8*)(hb + SWZH(ln, 416u + mq * 8u));
#pragma unroll
      for (int nt = 0; nt < 4; ++nt) acc[nt] = MFMA16(a, bsA[nt], acc[nt], 0, 0, 0);
    }
    {
      bf16x8 a = *(const bf16x8*)(hb + SWZH(ln, 448u + mq * 8u));
#pragma unroll
      for (int nt = 0; nt < 4; ++nt) acc[nt] = MFMA16(a, bsB[nt], acc[nt], 0, 0, 0);
    }
    {
      bf16x8 a = *(const bf16x8*)(hb + SWZH(ln, 480u + mq * 8u));
#pragma unroll
      for (int nt = 0; nt < 4; ++nt) acc[nt] = MFMA16(a, bsC[nt], acc[nt], 0, 0, 0);
    }
    // reload stream for next step (same addresses -> L2 hits; long slack)
#pragma unroll
    for (int nt = 0; nt < 4; ++nt) {
      const unsigned short* base = Whb + (nb + nt * 16u + ln) * 512u + mq * 8u;
      bsA[nt] = *(const bf16x8*)(base + 416u);
      bsB[nt] = *(const bf16x8*)(base + 448u);
      bsC[nt] = *(const bf16x8*)(base + 480u);
    }

    // VGPR-stationary chunks 0..9
#pragma unroll
    for (int c = 0; c < 10; ++c) {
      bf16x8 a = *(const bf16x8*)(hb + SWZH(ln, (unsigned)c * 32u + mq * 8u));
#pragma unroll
      for (int nt = 0; nt < 4; ++nt) acc[nt] = MFMA16(a, bo[c][nt], acc[nt], 0, 0, 0);
    }

    // LDS-resident chunks 10..12 ([c][n][32])
#pragma unroll
    for (int c = 0; c < 3; ++c) {
      bf16x8 a = *(const bf16x8*)(hb + SWZH(ln, 320u + (unsigned)c * 32u + mq * 8u));
      bf16x8 bl[4];
#pragma unroll
      for (int nt = 0; nt < 4; ++nt)
        bl[nt] = *(const bf16x8*)(whs + (unsigned)c * 16384u + (nb + nt * 16u + ln) * 32u + mq * 8u);
#pragma unroll
      for (int nt = 0; nt < 4; ++nt) acc[nt] = MFMA16(a, bl[nt], acc[nt], 0, 0, 0);
    }

    // u add + tanh -> h ; fused LDS + Hs stores (no persistent h16 array)
    const unsigned t = st - 1u;
#pragma unroll
    for (int nt = 0; nt < 4; ++nt)
#pragma unroll
      for (int j = 0; j < 4; ++j) {
        float u = __builtin_bit_cast(float, (unsigned)(unsigned short)uu[nt][j] << 16);
        float s = acc[nt][j] + u;
        float e2 = __expf(2.f * s);
        float h = 1.f - 2.f / (e2 + 1.f);     // tanh(s)
        unsigned short hv = f2bf(h);
        unsigned m = mq * 4u + j;
        unsigned n = nb + nt * 16u + ln;
        hn[SWZH(m, n)] = hv;
        Hs[(m * (unsigned)LSEQ + t) * 512u + n] = hv;
      }

    // next-u prefetch
    const unsigned tn = (st < (unsigned)LSEQ) ? st : ((unsigned)LSEQ - 1u);
#pragma unroll
    for (int nt = 0; nt < 4; ++nt)
      uu[nt] = *(const s16x4*)(Ubf + (tn * 512u + nb + nt * 16u + ln) * 16u + mq * 4u);

    // barrier WITHOUT vmcnt drain (LDS ops only)
    __builtin_amdgcn_sched_barrier(0);
    asm volatile("s_waitcnt lgkmcnt(0)" ::: "memory");
    __builtin_amdgcn_s_barrier();
    __builtin_amdgcn_sched_barrier(0);

    cur ^= 1u;
  }
}

// ---------------------------------------------------------------------------
// GEMM3 + GLU + residual: Y[r,e]=sum_d Hs[r,d]*Wfb[e,d]+bffn[e]; paired g-tile
// at e+512; out[r,e] = a*sigmoid(g) + x[r,e]  (fp32, overwrites d_out)
// ---------------------------------------------------------------------------
__global__ __launch_bounds__(256) void gemm_ffn_kernel(
    const unsigned short* __restrict__ A, const unsigned short* __restrict__ Bw,
    const float* __restrict__ bffn, const float* __restrict__ x,
    float* __restrict__ out)
{
  __shared__ __align__(16) unsigned char lds[24576]; // A 8KB | Ba 8KB | Bg 8KB
  const unsigned tid = threadIdx.x;
  const unsigned lid = tid & 63u, wid = tid >> 6;
  const unsigned wr = wid >> 1, wc = wid & 1u;
  const unsigned rbase = blockIdx.x * 128u, nbase = blockIdx.y * 128u;

  f32x4 acc_a[4][4] = {}, acc_g[4][4] = {};
  for (int kt = 0; kt < 16; ++kt) {
    __syncthreads();
#pragma unroll
    for (int i = 0; i < 2; ++i) {
      unsigned c = i * 256u + tid;
      const unsigned short* ga = A + (rbase + (c >> 2)) * 512u + kt * 32u + (c & 3u) * 8u;
      __builtin_amdgcn_global_load_lds(AS1(ga), AS3(lds + c * 16u), 16, 0, 0);
      const unsigned short* gb = Bw + (nbase + (c >> 2)) * 512u + kt * 32u + (c & 3u) * 8u;
      __builtin_amdgcn_global_load_lds(AS1(gb), AS3(lds + 8192u + c * 16u), 16, 0, 0);
      const unsigned short* gg = Bw + (512u + nbase + (c >> 2)) * 512u + kt * 32u + (c & 3u) * 8u;
      __builtin_amdgcn_global_load_lds(AS1(gg), AS3(lds + 16384u + c * 16u), 16, 0, 0);
    }
    __syncthreads();
    bf16x8 af[4], ba[4], bg[4];
#pragma unroll
    for (int mi = 0; mi < 4; ++mi)
      af[mi] = *(const bf16x8*)(lds + (wr * 64u + mi * 16u + (lid & 15u)) * 64u + (lid >> 4) * 16u);
#pragma unroll
    for (int ni = 0; ni < 4; ++ni) {
      ba[ni] = *(const bf16x8*)(lds + 8192u  + (wc * 64u + ni * 16u + (lid & 15u)) * 64u + (lid >> 4) * 16u);
      bg[ni] = *(const bf16x8*)(lds + 16384u + (wc * 64u + ni * 16u + (lid & 15u)) * 64u + (lid >> 4) * 16u);
    }
#pragma unroll
    for (int mi = 0; mi < 4; ++mi)
#pragma unroll
      for (int ni = 0; ni < 4; ++ni) {
        acc_a[mi][ni] = MFMA16(af[mi], ba[ni], acc_a[mi][ni], 0, 0, 0);
        acc_g[mi][ni] = MFMA16(af[mi], bg[ni], acc_g[mi][ni], 0, 0, 0);
      }
  }
#pragma unroll
  for (int mi = 0; mi < 4; ++mi)
#pragma unroll
    for (int ni = 0; ni < 4; ++ni) {
      unsigned e = nbase + wc * 64u + ni * 16u + (lid & 15u);
      float bba = bffn[e], bbg = bffn[e + 512u];
#pragma unroll
      for (int j = 0; j < 4; ++j) {
        unsigned r = rbase + wr * 64u + mi * 16u + (lid >> 4) * 4u + j;
        float a  = acc_a[mi][ni][j] + bba;
        float gg = acc_g[mi][ni][j] + bbg;
        float sg = 1.f / (1.f + __expf(-gg));
        out[r * 512u + e] = a * sg + x[r * 512u + e];
      }
    }
}

// ---------------------------------------------------------------------------
extern "C" void kernel_launch(void* const* d_in, const int* in_sizes, int n_in,
                              void* d_out, int out_size, void* d_ws, size_t ws_size,
                              hipStream_t stream) {
  const float* x     = (const float*)d_in[0];
  const float* gamma = (const float*)d_in[1];
  const float* beta  = (const float*)d_in[2];
  const float* mean  = (const float*)d_in[3];
  const float* var   = (const float*)d_in[4];
  const float* Wx    = (const float*)d_in[5];
  const float* Wh    = (const float*)d_in[6];
  const float* brnn  = (const float*)d_in[7];
  const float* Wffn  = (const float*)d_in[8];
  const float* bffn  = (const float*)d_in[9];
  float* out = (float*)d_out;

  // workspace layout
  unsigned char* ws = (unsigned char*)d_ws;
  unsigned short* Hs   = (unsigned short*)(ws);                     // 32 MB
  unsigned short* Xbf  = (unsigned short*)(ws + (size_t)33554432);  // 32 MB
  unsigned short* Wxp  = (unsigned short*)(ws + (size_t)67108864);  // 512 KB
  unsigned short* Wfb  = (unsigned short*)(ws + (size_t)67633152);  // 1 MB
  unsigned short* Whb  = (unsigned short*)(ws + (size_t)68681728);  // 512 KB
  float*          bpr  = (float*)        (ws + (size_t)69206016);   // 2 KB

  // Ubf (bf16 input projection, [t][n][m], 32MB) lives in d_out's first half;
  // fully consumed by rnn_rec, then gemm_ffn overwrites d_out with fp32 out.
  unsigned short* Ubf = (unsigned short*)d_out;

  prep_kernel<<<2048, 256, 0, stream>>>(Wx, gamma, beta, mean, var, brnn,
                                        Wffn, Wh, Wxp, Wfb, Whb, bpr);
  convx_kernel<<<2048, 256, 0, stream>>>(x, Xbf);
  gemm_u_kernel<<<dim3(256, 4), 256, 0, stream>>>(Xbf, Wxp, bpr, Ubf);
  rnn_rec_kernel<<<1, 512, 0, stream>>>(Whb, Ubf, Hs);
  gemm_ffn_kernel<<<dim3(256, 4), 256, 0, stream>>>(Hs, Wfb, bffn, x, out);
}

// Round 10
// 8165.041 us; speedup vs baseline: 1.9481x; 1.9481x over previous
//
#include <hip/hip_runtime.h>
#include <math.h>

// Problem constants
#define DD   512
#define LSEQ 2048
#define NBAT 16
#define RTOT (NBAT * LSEQ)   // 32768 rows

typedef __attribute__((ext_vector_type(8))) short bf16x8;
typedef __attribute__((ext_vector_type(4))) short s16x4;
typedef __attribute__((ext_vector_type(4))) float f32x4;

#define AS1(p) ((const __attribute__((address_space(1))) void*)(p))
#define AS3(p) ((__attribute__((address_space(3))) void*)(p))
#define MFMA16 __builtin_amdgcn_mfma_f32_16x16x32_bf16

__device__ __forceinline__ unsigned short f2bf(float f) {
  unsigned u = __builtin_bit_cast(unsigned, f);
  u += 0x7fffu + ((u >> 16) & 1u);
  return (unsigned short)(u >> 16);
}

// ---------------------------------------------------------------------------
// prep: fold BN into Wx (Wx' = Wx*diag(inv), b' = Wx(beta-mean*iv)+b_rnn),
// convert Wffn and Wh to bf16.
// blocks 0..511: Wx'+b' ; 512..1535: Wffn ; 1536..2047: Wh.
// ---------------------------------------------------------------------------
__global__ __launch_bounds__(256) void prep_kernel(
    const float* __restrict__ Wx, const float* __restrict__ gamma,
    const float* __restrict__ beta, const float* __restrict__ mean,
    const float* __restrict__ var, const float* __restrict__ brnn,
    const float* __restrict__ Wffn, const float* __restrict__ Wh,
    unsigned short* __restrict__ Wxp, unsigned short* __restrict__ Wfb,
    unsigned short* __restrict__ Whb, float* __restrict__ bprime)
{
  const unsigned tid = threadIdx.x, bx = blockIdx.x;
  if (bx < 512) {
    __shared__ float red[256];
    float partial = 0.f;
#pragma unroll
    for (int i = 0; i < 2; ++i) {
      unsigned d = i * 256u + tid;
      float iv = gamma[d] * rsqrtf(var[d] + 1e-5f);
      float w  = Wx[bx * 512u + d];
      Wxp[bx * 512u + d] = (unsigned short)f2bf(w * iv);
      partial += w * (beta[d] - mean[d] * iv);
    }
    red[tid] = partial; __syncthreads();
    for (unsigned s = 128; s > 0; s >>= 1) {
      if (tid < s) red[tid] += red[tid + s];
      __syncthreads();
    }
    if (tid == 0) bprime[bx] = red[0] + brnn[bx];
  } else if (bx < 1536) {
    unsigned row = bx - 512;
#pragma unroll
    for (int i = 0; i < 2; ++i) {
      unsigned d = i * 256u + tid;
      Wfb[row * 512u + d] = (unsigned short)f2bf(Wffn[row * 512u + d]);
    }
  } else {
    unsigned row = bx - 1536;
#pragma unroll
    for (int i = 0; i < 2; ++i) {
      unsigned d = i * 256u + tid;
      Whb[row * 512u + d] = (unsigned short)f2bf(Wh[row * 512u + d]);
    }
  }
}

// ---------------------------------------------------------------------------
// convert x (fp32) -> bf16, row-major (RTOT, D)
// ---------------------------------------------------------------------------
__global__ __launch_bounds__(256) void convx_kernel(
    const float* __restrict__ x, unsigned short* __restrict__ Xbf)
{
  const unsigned total4 = RTOT * DD / 4;
  unsigned i = blockIdx.x * 256u + threadIdx.x;
  const unsigned stride = gridDim.x * 256u;
  const float4* __restrict__ x4 = (const float4*)x;
  for (; i < total4; i += stride) {
    float4 v = x4[i];
    unsigned short o0 = f2bf(v.x), o1 = f2bf(v.y), o2 = f2bf(v.z), o3 = f2bf(v.w);
    unsigned long long pack = (unsigned long long)o0 |
                              ((unsigned long long)o1 << 16) |
                              ((unsigned long long)o2 << 32) |
                              ((unsigned long long)o3 << 48);
    *(unsigned long long*)(Xbf + i * 4u) = pack;
  }
}

// ---------------------------------------------------------------------------
// GEMM1: Ubf[t][n][m] = bf16( sum_d Xbf[r,d]*Wxp[n,d] + b'[n] ), r = m*L + t.
// [t][n][m] layout => rnn_rec's per-step u prefetch is 8B coalesced loads.
// ---------------------------------------------------------------------------
__global__ __launch_bounds__(256) void gemm_u_kernel(
    const unsigned short* __restrict__ A, const unsigned short* __restrict__ Bw,
    const float* __restrict__ bias, unsigned short* __restrict__ Ubf)
{
  __shared__ __align__(16) unsigned char lds[16384]; // A 8KB | B 8KB
  const unsigned tid = threadIdx.x;
  const unsigned lid = tid & 63u, wid = tid >> 6;
  const unsigned wr = wid >> 1, wc = wid & 1u;
  const unsigned rbase = blockIdx.x * 128u, nbase = blockIdx.y * 128u;

  f32x4 acc[4][4] = {};
  for (int kt = 0; kt < 16; ++kt) {
    __syncthreads();
#pragma unroll
    for (int i = 0; i < 2; ++i) {
      unsigned c = i * 256u + tid;
      const unsigned short* g = A + (rbase + (c >> 2)) * 512u + kt * 32u + (c & 3u) * 8u;
      __builtin_amdgcn_global_load_lds(AS1(g), AS3(lds + c * 16u), 16, 0, 0);
    }
#pragma unroll
    for (int i = 0; i < 2; ++i) {
      unsigned c = i * 256u + tid;
      const unsigned short* g = Bw + (nbase + (c >> 2)) * 512u + kt * 32u + (c & 3u) * 8u;
      __builtin_amdgcn_global_load_lds(AS1(g), AS3(lds + 8192u + c * 16u), 16, 0, 0);
    }
    __syncthreads();
    bf16x8 af[4], bfr[4];
#pragma unroll
    for (int mi = 0; mi < 4; ++mi)
      af[mi] = *(const bf16x8*)(lds + (wr * 64u + mi * 16u + (lid & 15u)) * 64u + (lid >> 4) * 16u);
#pragma unroll
    for (int ni = 0; ni < 4; ++ni)
      bfr[ni] = *(const bf16x8*)(lds + 8192u + (wc * 64u + ni * 16u + (lid & 15u)) * 64u + (lid >> 4) * 16u);
#pragma unroll
    for (int mi = 0; mi < 4; ++mi)
#pragma unroll
      for (int ni = 0; ni < 4; ++ni)
        acc[mi][ni] = MFMA16(af[mi], bfr[ni], acc[mi][ni], 0, 0, 0);
  }
#pragma unroll
  for (int mi = 0; mi < 4; ++mi)
#pragma unroll
    for (int ni = 0; ni < 4; ++ni) {
      unsigned e = nbase + wc * 64u + ni * 16u + (lid & 15u);
      float bb = bias[e];
#pragma unroll
      for (int j = 0; j < 4; ++j) {
        unsigned r = rbase + wr * 64u + mi * 16u + (lid >> 4) * 4u + j;
        unsigned t = r & 2047u, b = r >> 11u;
        Ubf[(t * 512u + e) * 16u + b] = f2bf(acc[mi][ni][j] + bb);
      }
    }
}

// ---------------------------------------------------------------------------
// Recurrence, SINGLE-CU v4: 1 WG x 256 thr (4 waves, 1/SIMD) — the config the
// compiler provably gives 256 arch VGPRs (+AGPRs) [R6 measured]. Wave w owns
// N=128 cols (8 n-tiles). Wh: chunks 0..11 (k<384) STATIONARY in registers
// (384 regs/lane); chunks 12..15 in LDS (128KB, lane-contiguous frag layout,
// conflict-free b128); NOTHING streamed — steady-state external traffic is
// u-loads (16KB) + Hs-stores (16KB) per step only.
// h: single 16KB LDS buffer in [chunk][perm(lane)] frag layout (conflict-free
// b128 reads, 4-way b16 writes); 2 lgkm-only barriers/step (no vmcnt drain).
// ---------------------------------------------------------------------------
__global__ __launch_bounds__(256, 1) void rnn_rec_kernel(
    const unsigned short* __restrict__ Whb,
    const unsigned short* __restrict__ Ubf,
    unsigned short* __restrict__ Hs)
{
  __shared__ unsigned short hlds[8192];    // 16 KB: [c][perm(l)][8]
  __shared__ unsigned short wlds[65536];   // 128 KB: [(w*4+ci)*8+nt][lane][8]

  const unsigned tid = threadIdx.x, lid = tid & 63u, w = tid >> 6;
  const unsigned mq = lid >> 4, ln = lid & 15u;
  const unsigned nb = w * 128u;
  // A-frag read permutation: perm(l) = (l&48) | ((l&3)<<2) | ((l>>2)&3)
  const unsigned perm8 = ((lid & 48u) | ((lid & 3u) << 2) | ((lid >> 2) & 3u)) * 8u;

  // h0 = 0
  for (unsigned i = tid; i < 8192u; i += 256u) hlds[i] = 0;
  // stage Wh chunks 12..15 into wlds (lane-contiguous: write==read addr)
#pragma unroll
  for (int ci = 0; ci < 4; ++ci)
#pragma unroll
    for (int nt = 0; nt < 8; ++nt)
      *(bf16x8*)(wlds + ((w * 4u + ci) * 8u + nt) * 512u + lid * 8u) =
        *(const bf16x8*)(Whb + (nb + nt * 16u + ln) * 512u + (12u + ci) * 32u + mq * 8u);

  // stationary B fragments: chunks 0..11 (k < 384) -> 384 regs/lane
  bf16x8 bo[12][8];
#pragma unroll
  for (int c = 0; c < 12; ++c)
#pragma unroll
    for (int nt = 0; nt < 8; ++nt)
      bo[c][nt] = *(const bf16x8*)(Whb + (nb + nt * 16u + ln) * 512u + (unsigned)c * 32u + mq * 8u);

  // per-lane constants for the h-write addressing:
  // dst(nt,j) = c*512 + sub*128 + j*32 + mq*8 + jl,  n = nb+nt*16+ln
  unsigned hdst[8];
#pragma unroll
  for (int nt = 0; nt < 8; ++nt) {
    unsigned n = nb + nt * 16u + ln;
    hdst[nt] = (n >> 5) * 512u + ((n >> 3) & 3u) * 128u + mq * 8u + (n & 7u);
  }

  // u for step 1 (t=0)
  s16x4 uu[8];
#pragma unroll
  for (int nt = 0; nt < 8; ++nt)
    uu[nt] = *(const s16x4*)(Ubf + (0u * 512u + nb + nt * 16u + ln) * 16u + mq * 4u);

  __syncthreads();

  for (unsigned t = 0; t < (unsigned)LSEQ; ++t) {
    f32x4 acc[8] = {};

    // ---- phase 1: MFMAs (reads h from hlds) ----
#pragma unroll
    for (int c = 0; c < 12; ++c) {
      bf16x8 a = *(const bf16x8*)(hlds + (unsigned)c * 512u + perm8);
#pragma unroll
      for (int nt = 0; nt < 8; ++nt)
        acc[nt] = MFMA16(a, bo[c][nt], acc[nt], 0, 0, 0);
    }
#pragma unroll
    for (int ci = 0; ci < 4; ++ci) {
      bf16x8 a = *(const bf16x8*)(hlds + (12u + ci) * 512u + perm8);
      bf16x8 bl[8];
#pragma unroll
      for (int nt = 0; nt < 8; ++nt)
        bl[nt] = *(const bf16x8*)(wlds + ((w * 4u + ci) * 8u + nt) * 512u + lid * 8u);
#pragma unroll
      for (int nt = 0; nt < 8; ++nt)
        acc[nt] = MFMA16(a, bl[nt], acc[nt], 0, 0, 0);
    }

    // all h reads done (this wave); wait CU-wide before overwriting h
    __builtin_amdgcn_sched_barrier(0);
    asm volatile("s_waitcnt lgkmcnt(0)" ::: "memory");
    __builtin_amdgcn_s_barrier();
    __builtin_amdgcn_sched_barrier(0);

    // ---- phase 2: u add + tanh, write h (LDS) + Hs (global), prefetch u ----
#pragma unroll
    for (int nt = 0; nt < 8; ++nt) {
      unsigned n = nb + nt * 16u + ln;
#pragma unroll
      for (int j = 0; j < 4; ++j) {
        float uf = __builtin_bit_cast(float, (unsigned)(unsigned short)uu[nt][j] << 16);
        float s = acc[nt][j] + uf;
        float e2 = __expf(2.f * s);
        float h = 1.f - 2.f / (e2 + 1.f);     // tanh(s)
        unsigned short hv = f2bf(h);
        hlds[hdst[nt] + (unsigned)j * 32u] = hv;
        Hs[((mq * 4u + (unsigned)j) * (unsigned)LSEQ + t) * 512u + n] = hv;
      }
    }
    // next-u prefetch (full-step slack; rides past barriers, no vmcnt drain)
    const unsigned tn = (t + 1u < (unsigned)LSEQ) ? (t + 1u) : t;
#pragma unroll
    for (int nt = 0; nt < 8; ++nt)
      uu[nt] = *(const s16x4*)(Ubf + (tn * 512u + nb + nt * 16u + ln) * 16u + mq * 4u);

    __builtin_amdgcn_sched_barrier(0);
    asm volatile("s_waitcnt lgkmcnt(0)" ::: "memory");
    __builtin_amdgcn_s_barrier();
    __builtin_amdgcn_sched_barrier(0);
  }
}

// ---------------------------------------------------------------------------
// GEMM3 + GLU + residual: Y[r,e]=sum_d Hs[r,d]*Wfb[e,d]+bffn[e]; paired g-tile
// at e+512; out[r,e] = a*sigmoid(g) + x[r,e]  (fp32, overwrites d_out)
// ---------------------------------------------------------------------------
__global__ __launch_bounds__(256) void gemm_ffn_kernel(
    const unsigned short* __restrict__ A, const unsigned short* __restrict__ Bw,
    const float* __restrict__ bffn, const float* __restrict__ x,
    float* __restrict__ out)
{
  __shared__ __align__(16) unsigned char lds[24576]; // A 8KB | Ba 8KB | Bg 8KB
  const unsigned tid = threadIdx.x;
  const unsigned lid = tid & 63u, wid = tid >> 6;
  const unsigned wr = wid >> 1, wc = wid & 1u;
  const unsigned rbase = blockIdx.x * 128u, nbase = blockIdx.y * 128u;

  f32x4 acc_a[4][4] = {}, acc_g[4][4] = {};
  for (int kt = 0; kt < 16; ++kt) {
    __syncthreads();
#pragma unroll
    for (int i = 0; i < 2; ++i) {
      unsigned c = i * 256u + tid;
      const unsigned short* ga = A + (rbase + (c >> 2)) * 512u + kt * 32u + (c & 3u) * 8u;
      __builtin_amdgcn_global_load_lds(AS1(ga), AS3(lds + c * 16u), 16, 0, 0);
      const unsigned short* gb = Bw + (nbase + (c >> 2)) * 512u + kt * 32u + (c & 3u) * 8u;
      __builtin_amdgcn_global_load_lds(AS1(gb), AS3(lds + 8192u + c * 16u), 16, 0, 0);
      const unsigned short* gg = Bw + (512u + nbase + (c >> 2)) * 512u + kt * 32u + (c & 3u) * 8u;
      __builtin_amdgcn_global_load_lds(AS1(gg), AS3(lds + 16384u + c * 16u), 16, 0, 0);
    }
    __syncthreads();
    bf16x8 af[4], ba[4], bg[4];
#pragma unroll
    for (int mi = 0; mi < 4; ++mi)
      af[mi] = *(const bf16x8*)(lds + (wr * 64u + mi * 16u + (lid & 15u)) * 64u + (lid >> 4) * 16u);
#pragma unroll
    for (int ni = 0; ni < 4; ++ni) {
      ba[ni] = *(const bf16x8*)(lds + 8192u  + (wc * 64u + ni * 16u + (lid & 15u)) * 64u + (lid >> 4) * 16u);
      bg[ni] = *(const bf16x8*)(lds + 16384u + (wc * 64u + ni * 16u + (lid & 15u)) * 64u + (lid >> 4) * 16u);
    }
#pragma unroll
    for (int mi = 0; mi < 4; ++mi)
#pragma unroll
      for (int ni = 0; ni < 4; ++ni) {
        acc_a[mi][ni] = MFMA16(af[mi], ba[ni], acc_a[mi][ni], 0, 0, 0);
        acc_g[mi][ni] = MFMA16(af[mi], bg[ni], acc_g[mi][ni], 0, 0, 0);
      }
  }
#pragma unroll
  for (int mi = 0; mi < 4; ++mi)
#pragma unroll
    for (int ni = 0; ni < 4; ++ni) {
      unsigned e = nbase + wc * 64u + ni * 16u + (lid & 15u);
      float bba = bffn[e], bbg = bffn[e + 512u];
#pragma unroll
      for (int j = 0; j < 4; ++j) {
        unsigned r = rbase + wr * 64u + mi * 16u + (lid >> 4) * 4u + j;
        float a  = acc_a[mi][ni][j] + bba;
        float gg = acc_g[mi][ni][j] + bbg;
        float sg = 1.f / (1.f + __expf(-gg));
        out[r * 512u + e] = a * sg + x[r * 512u + e];
      }
    }
}

// ---------------------------------------------------------------------------
extern "C" void kernel_launch(void* const* d_in, const int* in_sizes, int n_in,
                              void* d_out, int out_size, void* d_ws, size_t ws_size,
                              hipStream_t stream) {
  const float* x     = (const float*)d_in[0];
  const float* gamma = (const float*)d_in[1];
  const float* beta  = (const float*)d_in[2];
  const float* mean  = (const float*)d_in[3];
  const float* var   = (const float*)d_in[4];
  const float* Wx    = (const float*)d_in[5];
  const float* Wh    = (const float*)d_in[6];
  const float* brnn  = (const float*)d_in[7];
  const float* Wffn  = (const float*)d_in[8];
  const float* bffn  = (const float*)d_in[9];
  float* out = (float*)d_out;

  // workspace layout
  unsigned char* ws = (unsigned char*)d_ws;
  unsigned short* Hs   = (unsigned short*)(ws);                     // 32 MB
  unsigned short* Xbf  = (unsigned short*)(ws + (size_t)33554432);  // 32 MB
  unsigned short* Wxp  = (unsigned short*)(ws + (size_t)67108864);  // 512 KB
  unsigned short* Wfb  = (unsigned short*)(ws + (size_t)67633152);  // 1 MB
  unsigned short* Whb  = (unsigned short*)(ws + (size_t)68681728);  // 512 KB
  float*          bpr  = (float*)        (ws + (size_t)69206016);   // 2 KB

  // Ubf (bf16 input projection, [t][n][m], 32MB) lives in d_out's first half;
  // fully consumed by rnn_rec, then gemm_ffn overwrites d_out with fp32 out.
  unsigned short* Ubf = (unsigned short*)d_out;

  prep_kernel<<<2048, 256, 0, stream>>>(Wx, gamma, beta, mean, var, brnn,
                                        Wffn, Wh, Wxp, Wfb, Whb, bpr);
  convx_kernel<<<2048, 256, 0, stream>>>(x, Xbf);
  gemm_u_kernel<<<dim3(256, 4), 256, 0, stream>>>(Xbf, Wxp, bpr, Ubf);
  rnn_rec_kernel<<<1, 256, 0, stream>>>(Whb, Ubf, Hs);
  gemm_ffn_kernel<<<dim3(256, 4), 256, 0, stream>>>(Hs, Wfb, bffn, x, out);
}

// Round 11
// 7048.311 us; speedup vs baseline: 2.2567x; 1.1584x over previous
//
#include <hip/hip_runtime.h>
#include <math.h>

// Problem constants
#define DD   512
#define LSEQ 2048
#define NBAT 16
#define RTOT (NBAT * LSEQ)   // 32768 rows

typedef __attribute__((ext_vector_type(8))) short bf16x8;
typedef __attribute__((ext_vector_type(4))) short s16x4;
typedef __attribute__((ext_vector_type(4))) float f32x4;

#define AS1(p) ((const __attribute__((address_space(1))) void*)(p))
#define AS3(p) ((__attribute__((address_space(3))) void*)(p))
#define MFMA16 __builtin_amdgcn_mfma_f32_16x16x32_bf16

__device__ __forceinline__ unsigned short f2bf(float f) {
  unsigned u = __builtin_bit_cast(unsigned, f);
  u += 0x7fffu + ((u >> 16) & 1u);
  return (unsigned short)(u >> 16);
}

// ---------------------------------------------------------------------------
// prep: fold BN into Wx (Wx' = Wx*diag(inv), b' = Wx(beta-mean*iv)+b_rnn),
// convert Wffn and Wh to bf16.
// blocks 0..511: Wx'+b' ; 512..1535: Wffn ; 1536..2047: Wh.
// ---------------------------------------------------------------------------
__global__ __launch_bounds__(256) void prep_kernel(
    const float* __restrict__ Wx, const float* __restrict__ gamma,
    const float* __restrict__ beta, const float* __restrict__ mean,
    const float* __restrict__ var, const float* __restrict__ brnn,
    const float* __restrict__ Wffn, const float* __restrict__ Wh,
    unsigned short* __restrict__ Wxp, unsigned short* __restrict__ Wfb,
    unsigned short* __restrict__ Whb, float* __restrict__ bprime)
{
  const unsigned tid = threadIdx.x, bx = blockIdx.x;
  if (bx < 512) {
    __shared__ float red[256];
    float partial = 0.f;
#pragma unroll
    for (int i = 0; i < 2; ++i) {
      unsigned d = i * 256u + tid;
      float iv = gamma[d] * rsqrtf(var[d] + 1e-5f);
      float w  = Wx[bx * 512u + d];
      Wxp[bx * 512u + d] = (unsigned short)f2bf(w * iv);
      partial += w * (beta[d] - mean[d] * iv);
    }
    red[tid] = partial; __syncthreads();
    for (unsigned s = 128; s > 0; s >>= 1) {
      if (tid < s) red[tid] += red[tid + s];
      __syncthreads();
    }
    if (tid == 0) bprime[bx] = red[0] + brnn[bx];
  } else if (bx < 1536) {
    unsigned row = bx - 512;
#pragma unroll
    for (int i = 0; i < 2; ++i) {
      unsigned d = i * 256u + tid;
      Wfb[row * 512u + d] = (unsigned short)f2bf(Wffn[row * 512u + d]);
    }
  } else {
    unsigned row = bx - 1536;
#pragma unroll
    for (int i = 0; i < 2; ++i) {
      unsigned d = i * 256u + tid;
      Whb[row * 512u + d] = (unsigned short)f2bf(Wh[row * 512u + d]);
    }
  }
}

// ---------------------------------------------------------------------------
// convert x (fp32) -> bf16, row-major (RTOT, D)
// ---------------------------------------------------------------------------
__global__ __launch_bounds__(256) void convx_kernel(
    const float* __restrict__ x, unsigned short* __restrict__ Xbf)
{
  const unsigned total4 = RTOT * DD / 4;
  unsigned i = blockIdx.x * 256u + threadIdx.x;
  const unsigned stride = gridDim.x * 256u;
  const float4* __restrict__ x4 = (const float4*)x;
  for (; i < total4; i += stride) {
    float4 v = x4[i];
    unsigned short o0 = f2bf(v.x), o1 = f2bf(v.y), o2 = f2bf(v.z), o3 = f2bf(v.w);
    unsigned long long pack = (unsigned long long)o0 |
                              ((unsigned long long)o1 << 16) |
                              ((unsigned long long)o2 << 32) |
                              ((unsigned long long)o3 << 48);
    *(unsigned long long*)(Xbf + i * 4u) = pack;
  }
}

// ---------------------------------------------------------------------------
// GEMM1: Ubf[t][n][m] = bf16( sum_d Xbf[r,d]*Wxp[n,d] + b'[n] ), r = m*L + t.
// [t][n][m] layout => rnn_rec's per-step u prefetch is 8B coalesced loads.
// ---------------------------------------------------------------------------
__global__ __launch_bounds__(256) void gemm_u_kernel(
    const unsigned short* __restrict__ A, const unsigned short* __restrict__ Bw,
    const float* __restrict__ bias, unsigned short* __restrict__ Ubf)
{
  __shared__ __align__(16) unsigned char lds[16384]; // A 8KB | B 8KB
  const unsigned tid = threadIdx.x;
  const unsigned lid = tid & 63u, wid = tid >> 6;
  const unsigned wr = wid >> 1, wc = wid & 1u;
  const unsigned rbase = blockIdx.x * 128u, nbase = blockIdx.y * 128u;

  f32x4 acc[4][4] = {};
  for (int kt = 0; kt < 16; ++kt) {
    __syncthreads();
#pragma unroll
    for (int i = 0; i < 2; ++i) {
      unsigned c = i * 256u + tid;
      const unsigned short* g = A + (rbase + (c >> 2)) * 512u + kt * 32u + (c & 3u) * 8u;
      __builtin_amdgcn_global_load_lds(AS1(g), AS3(lds + c * 16u), 16, 0, 0);
    }
#pragma unroll
    for (int i = 0; i < 2; ++i) {
      unsigned c = i * 256u + tid;
      const unsigned short* g = Bw + (nbase + (c >> 2)) * 512u + kt * 32u + (c & 3u) * 8u;
      __builtin_amdgcn_global_load_lds(AS1(g), AS3(lds + 8192u + c * 16u), 16, 0, 0);
    }
    __syncthreads();
    bf16x8 af[4], bfr[4];
#pragma unroll
    for (int mi = 0; mi < 4; ++mi)
      af[mi] = *(const bf16x8*)(lds + (wr * 64u + mi * 16u + (lid & 15u)) * 64u + (lid >> 4) * 16u);
#pragma unroll
    for (int ni = 0; ni < 4; ++ni)
      bfr[ni] = *(const bf16x8*)(lds + 8192u + (wc * 64u + ni * 16u + (lid & 15u)) * 64u + (lid >> 4) * 16u);
#pragma unroll
    for (int mi = 0; mi < 4; ++mi)
#pragma unroll
      for (int ni = 0; ni < 4; ++ni)
        acc[mi][ni] = MFMA16(af[mi], bfr[ni], acc[mi][ni], 0, 0, 0);
  }
#pragma unroll
  for (int mi = 0; mi < 4; ++mi)
#pragma unroll
    for (int ni = 0; ni < 4; ++ni) {
      unsigned e = nbase + wc * 64u + ni * 16u + (lid & 15u);
      float bb = bias[e];
#pragma unroll
      for (int j = 0; j < 4; ++j) {
        unsigned r = rbase + wr * 64u + mi * 16u + (lid >> 4) * 4u + j;
        unsigned t = r & 2047u, b = r >> 11u;
        Ubf[(t * 512u + e) * 16u + b] = f2bf(acc[mi][ni][j] + bb);
      }
    }
}

// ---------------------------------------------------------------------------
// Recurrence, SINGLE-CU v5: 1 WG x 256 thr (4 waves, 1/SIMD, 248+ VGPR
// honored [R10 measured]). Wave w owns N=128 cols. Wh chunks 0..11 stationary
// in registers, 12..15 in LDS (128KB). h in 16KB LDS frag layout.
// v5 changes (VALU diet — R10 was 47% VALU on-CU from fp32 div + f2bf +
// scattered 2B stores):
//   - tanh: t=exp2(s*2log2e); h=(t-1)*v_rcp(t+1), s clamped to +-9 (no NaN).
//   - bf16 convert via v_cvt_pk_bf16_f32 (2 elems/inst, RTNE).
//   - Hs export moved to phase 1: re-read hlds as b128, store dwordx4
//     (4+4 ops/lane vs 32 scalar stores), overlaps MFMA phase.
// ---------------------------------------------------------------------------
__global__ __launch_bounds__(256, 1) void rnn_rec_kernel(
    const unsigned short* __restrict__ Whb,
    const unsigned short* __restrict__ Ubf,
    unsigned short* __restrict__ Hs)
{
  __shared__ unsigned short hlds[8192];    // 16 KB: [c][perm(l)][8]
  __shared__ unsigned short wlds[65536];   // 128 KB: [(w*4+ci)*8+nt][lane][8]

  const unsigned tid = threadIdx.x, lid = tid & 63u, w = tid >> 6;
  const unsigned mq = lid >> 4, ln = lid & 15u;
  const unsigned nb = w * 128u;
  // A-frag read permutation: perm(l) = (l&48) | ((l&3)<<2) | ((l>>2)&3)
  const unsigned perm8 = ((lid & 48u) | ((lid & 3u) << 2) | ((lid >> 2) & 3u)) * 8u;

  // export unit constants: m = tid&15, oct = (tid>>4)*4 + i
  const unsigned em = tid & 15u;
  const unsigned eo0 = (tid >> 4) * 4u;
  const unsigned ecm = (em & 3u) * 32u + (em >> 2) * 8u;

  // h0 = 0
  for (unsigned i = tid; i < 8192u; i += 256u) hlds[i] = 0;
  // stage Wh chunks 12..15 into wlds (lane-contiguous: write==read addr)
#pragma unroll
  for (int ci = 0; ci < 4; ++ci)
#pragma unroll
    for (int nt = 0; nt < 8; ++nt)
      *(bf16x8*)(wlds + ((w * 4u + ci) * 8u + nt) * 512u + lid * 8u) =
        *(const bf16x8*)(Whb + (nb + nt * 16u + ln) * 512u + (12u + ci) * 32u + mq * 8u);

  // stationary B fragments: chunks 0..11 (k < 384)
  bf16x8 bo[12][8];
#pragma unroll
  for (int c = 0; c < 12; ++c)
#pragma unroll
    for (int nt = 0; nt < 8; ++nt)
      bo[c][nt] = *(const bf16x8*)(Whb + (nb + nt * 16u + ln) * 512u + (unsigned)c * 32u + mq * 8u);

  // per-lane constants for the h-write addressing
  unsigned hdst[8];
#pragma unroll
  for (int nt = 0; nt < 8; ++nt) {
    unsigned n = nb + nt * 16u + ln;
    hdst[nt] = (n >> 5) * 512u + ((n >> 3) & 3u) * 128u + mq * 8u + (n & 7u);
  }

  // u for step 1 (t=0)
  s16x4 uu[8];
#pragma unroll
  for (int nt = 0; nt < 8; ++nt)
    uu[nt] = *(const s16x4*)(Ubf + (0u * 512u + nb + nt * 16u + ln) * 16u + mq * 4u);

  __syncthreads();

  for (unsigned t = 0; t < (unsigned)LSEQ; ++t) {
    // ---- phase 1: export h of previous step (packed), then MFMAs ----
    if (t > 0) {
#pragma unroll
      for (int i = 0; i < 4; ++i) {
        unsigned oct = eo0 + (unsigned)i;
        unsigned ea = (oct >> 2) * 512u + (oct & 3u) * 128u + ecm;
        bf16x8 v = *(const bf16x8*)(hlds + ea);
        *(bf16x8*)(Hs + (em * (unsigned)LSEQ + (t - 1u)) * 512u + oct * 8u) = v;
      }
    }

    f32x4 acc[8] = {};
#pragma unroll
    for (int c = 0; c < 12; ++c) {
      bf16x8 a = *(const bf16x8*)(hlds + (unsigned)c * 512u + perm8);
#pragma unroll
      for (int nt = 0; nt < 8; ++nt)
        acc[nt] = MFMA16(a, bo[c][nt], acc[nt], 0, 0, 0);
    }
#pragma unroll
    for (int ci = 0; ci < 4; ++ci) {
      bf16x8 a = *(const bf16x8*)(hlds + (12u + ci) * 512u + perm8);
      bf16x8 bl[8];
#pragma unroll
      for (int nt = 0; nt < 8; ++nt)
        bl[nt] = *(const bf16x8*)(wlds + ((w * 4u + ci) * 8u + nt) * 512u + lid * 8u);
#pragma unroll
      for (int nt = 0; nt < 8; ++nt)
        acc[nt] = MFMA16(a, bl[nt], acc[nt], 0, 0, 0);
    }

    // all hlds reads done (incl. export); wait CU-wide before overwriting h
    __builtin_amdgcn_sched_barrier(0);
    asm volatile("s_waitcnt lgkmcnt(0)" ::: "memory");
    __builtin_amdgcn_s_barrier();
    __builtin_amdgcn_sched_barrier(0);

    // ---- phase 2: u add + tanh (exp2+rcp), cvt_pk to bf16, write hlds ----
#pragma unroll
    for (int nt = 0; nt < 8; ++nt) {
      float hf[4];
#pragma unroll
      for (int j = 0; j < 4; ++j) {
        float uf = __builtin_bit_cast(float, (unsigned)(unsigned short)uu[nt][j] << 16);
        float s = acc[nt][j] + uf;
        s = fminf(fmaxf(s, -9.f), 9.f);                     // tanh saturates; avoids inf->NaN
        float t2 = __builtin_amdgcn_exp2f(s * 2.8853900818f); // e^(2s)
        hf[j] = (t2 - 1.f) * __builtin_amdgcn_rcpf(t2 + 1.f);
      }
      unsigned r0, r1;
      asm("v_cvt_pk_bf16_f32 %0, %1, %2" : "=v"(r0) : "v"(hf[0]), "v"(hf[1]));
      asm("v_cvt_pk_bf16_f32 %0, %1, %2" : "=v"(r1) : "v"(hf[2]), "v"(hf[3]));
      hlds[hdst[nt] + 0u]  = (unsigned short)r0;
      hlds[hdst[nt] + 32u] = (unsigned short)(r0 >> 16);
      hlds[hdst[nt] + 64u] = (unsigned short)r1;
      hlds[hdst[nt] + 96u] = (unsigned short)(r1 >> 16);
    }

    // next-u prefetch (full-step slack; no vmcnt drain at barriers)
    const unsigned tn = (t + 1u < (unsigned)LSEQ) ? (t + 1u) : t;
#pragma unroll
    for (int nt = 0; nt < 8; ++nt)
      uu[nt] = *(const s16x4*)(Ubf + (tn * 512u + nb + nt * 16u + ln) * 16u + mq * 4u);

    __builtin_amdgcn_sched_barrier(0);
    asm volatile("s_waitcnt lgkmcnt(0)" ::: "memory");
    __builtin_amdgcn_s_barrier();
    __builtin_amdgcn_sched_barrier(0);
  }

  // final export: hlds now holds h for column LSEQ-1
#pragma unroll
  for (int i = 0; i < 4; ++i) {
    unsigned oct = eo0 + (unsigned)i;
    unsigned ea = (oct >> 2) * 512u + (oct & 3u) * 128u + ecm;
    bf16x8 v = *(const bf16x8*)(hlds + ea);
    *(bf16x8*)(Hs + (em * (unsigned)LSEQ + ((unsigned)LSEQ - 1u)) * 512u + oct * 8u) = v;
  }
}

// ---------------------------------------------------------------------------
// GEMM3 + GLU + residual: Y[r,e]=sum_d Hs[r,d]*Wfb[e,d]+bffn[e]; paired g-tile
// at e+512; out[r,e] = a*sigmoid(g) + x[r,e]  (fp32, overwrites d_out)
// ---------------------------------------------------------------------------
__global__ __launch_bounds__(256) void gemm_ffn_kernel(
    const unsigned short* __restrict__ A, const unsigned short* __restrict__ Bw,
    const float* __restrict__ bffn, const float* __restrict__ x,
    float* __restrict__ out)
{
  __shared__ __align__(16) unsigned char lds[24576]; // A 8KB | Ba 8KB | Bg 8KB
  const unsigned tid = threadIdx.x;
  const unsigned lid = tid & 63u, wid = tid >> 6;
  const unsigned wr = wid >> 1, wc = wid & 1u;
  const unsigned rbase = blockIdx.x * 128u, nbase = blockIdx.y * 128u;

  f32x4 acc_a[4][4] = {}, acc_g[4][4] = {};
  for (int kt = 0; kt < 16; ++kt) {
    __syncthreads();
#pragma unroll
    for (int i = 0; i < 2; ++i) {
      unsigned c = i * 256u + tid;
      const unsigned short* ga = A + (rbase + (c >> 2)) * 512u + kt * 32u + (c & 3u) * 8u;
      __builtin_amdgcn_global_load_lds(AS1(ga), AS3(lds + c * 16u), 16, 0, 0);
      const unsigned short* gb = Bw + (nbase + (c >> 2)) * 512u + kt * 32u + (c & 3u) * 8u;
      __builtin_amdgcn_global_load_lds(AS1(gb), AS3(lds + 8192u + c * 16u), 16, 0, 0);
      const unsigned short* gg = Bw + (512u + nbase + (c >> 2)) * 512u + kt * 32u + (c & 3u) * 8u;
      __builtin_amdgcn_global_load_lds(AS1(gg), AS3(lds + 16384u + c * 16u), 16, 0, 0);
    }
    __syncthreads();
    bf16x8 af[4], ba[4], bg[4];
#pragma unroll
    for (int mi = 0; mi < 4; ++mi)
      af[mi] = *(const bf16x8*)(lds + (wr * 64u + mi * 16u + (lid & 15u)) * 64u + (lid >> 4) * 16u);
#pragma unroll
    for (int ni = 0; ni < 4; ++ni) {
      ba[ni] = *(const bf16x8*)(lds + 8192u  + (wc * 64u + ni * 16u + (lid & 15u)) * 64u + (lid >> 4) * 16u);
      bg[ni] = *(const bf16x8*)(lds + 16384u + (wc * 64u + ni * 16u + (lid & 15u)) * 64u + (lid >> 4) * 16u);
    }
#pragma unroll
    for (int mi = 0; mi < 4; ++mi)
#pragma unroll
      for (int ni = 0; ni < 4; ++ni) {
        acc_a[mi][ni] = MFMA16(af[mi], ba[ni], acc_a[mi][ni], 0, 0, 0);
        acc_g[mi][ni] = MFMA16(af[mi], bg[ni], acc_g[mi][ni], 0, 0, 0);
      }
  }
#pragma unroll
  for (int mi = 0; mi < 4; ++mi)
#pragma unroll
    for (int ni = 0; ni < 4; ++ni) {
      unsigned e = nbase + wc * 64u + ni * 16u + (lid & 15u);
      float bba = bffn[e], bbg = bffn[e + 512u];
#pragma unroll
      for (int j = 0; j < 4; ++j) {
        unsigned r = rbase + wr * 64u + mi * 16u + (lid >> 4) * 4u + j;
        float a  = acc_a[mi][ni][j] + bba;
        float gg = acc_g[mi][ni][j] + bbg;
        float sg = 1.f / (1.f + __expf(-gg));
        out[r * 512u + e] = a * sg + x[r * 512u + e];
      }
    }
}

// ---------------------------------------------------------------------------
extern "C" void kernel_launch(void* const* d_in, const int* in_sizes, int n_in,
                              void* d_out, int out_size, void* d_ws, size_t ws_size,
                              hipStream_t stream) {
  const float* x     = (const float*)d_in[0];
  const float* gamma = (const float*)d_in[1];
  const float* beta  = (const float*)d_in[2];
  const float* mean  = (const float*)d_in[3];
  const float* var   = (const float*)d_in[4];
  const float* Wx    = (const float*)d_in[5];
  const float* Wh    = (const float*)d_in[6];
  const float* brnn  = (const float*)d_in[7];
  const float* Wffn  = (const float*)d_in[8];
  const float* bffn  = (const float*)d_in[9];
  float* out = (float*)d_out;

  // workspace layout
  unsigned char* ws = (unsigned char*)d_ws;
  unsigned short* Hs   = (unsigned short*)(ws);                     // 32 MB
  unsigned short* Xbf  = (unsigned short*)(ws + (size_t)33554432);  // 32 MB
  unsigned short* Wxp  = (unsigned short*)(ws + (size_t)67108864);  // 512 KB
  unsigned short* Wfb  = (unsigned short*)(ws + (size_t)67633152);  // 1 MB
  unsigned short* Whb  = (unsigned short*)(ws + (size_t)68681728);  // 512 KB
  float*          bpr  = (float*)        (ws + (size_t)69206016);   // 2 KB

  // Ubf (bf16 input projection, [t][n][m], 32MB) lives in d_out's first half;
  // fully consumed by rnn_rec, then gemm_ffn overwrites d_out with fp32 out.
  unsigned short* Ubf = (unsigned short*)d_out;

  prep_kernel<<<2048, 256, 0, stream>>>(Wx, gamma, beta, mean, var, brnn,
                                        Wffn, Wh, Wxp, Wfb, Whb, bpr);
  convx_kernel<<<2048, 256, 0, stream>>>(x, Xbf);
  gemm_u_kernel<<<dim3(256, 4), 256, 0, stream>>>(Xbf, Wxp, bpr, Ubf);
  rnn_rec_kernel<<<1, 256, 0, stream>>>(Whb, Ubf, Hs);
  gemm_ffn_kernel<<<dim3(256, 4), 256, 0, stream>>>(Hs, Wfb, bffn, x, out);
}

// Round 12
// 6987.862 us; speedup vs baseline: 2.2762x; 1.0087x over previous
//
#include <hip/hip_runtime.h>
#include <math.h>

// Problem constants
#define DD   512
#define LSEQ 2048
#define NBAT 16
#define RTOT (NBAT * LSEQ)   // 32768 rows
#define SC2LOG2E 2.8853900817779268f   // 2*log2(e)

typedef __attribute__((ext_vector_type(8))) short bf16x8;
typedef __attribute__((ext_vector_type(2))) unsigned int u32x2;
typedef __attribute__((ext_vector_type(4))) float f32x4;

#define AS1(p) ((const __attribute__((address_space(1))) void*)(p))
#define AS3(p) ((__attribute__((address_space(3))) void*)(p))
#define MFMA16 __builtin_amdgcn_mfma_f32_16x16x32_bf16

__device__ __forceinline__ unsigned short f2bf(float f) {
  unsigned u = __builtin_bit_cast(unsigned, f);
  u += 0x7fffu + ((u >> 16) & 1u);
  return (unsigned short)(u >> 16);
}

// ---------------------------------------------------------------------------
// prep: fold BN into Wx (Wx' = Wx*diag(inv), b' = Wx(beta-mean*iv)+b_rnn),
// convert Wffn to bf16; convert Wh to bf16 PRESCALED by 2*log2(e).
// blocks 0..511: Wx'+b' ; 512..1535: Wffn ; 1536..2047: Wh.
// ---------------------------------------------------------------------------
__global__ __launch_bounds__(256) void prep_kernel(
    const float* __restrict__ Wx, const float* __restrict__ gamma,
    const float* __restrict__ beta, const float* __restrict__ mean,
    const float* __restrict__ var, const float* __restrict__ brnn,
    const float* __restrict__ Wffn, const float* __restrict__ Wh,
    unsigned short* __restrict__ Wxp, unsigned short* __restrict__ Wfb,
    unsigned short* __restrict__ Whb, float* __restrict__ bprime)
{
  const unsigned tid = threadIdx.x, bx = blockIdx.x;
  if (bx < 512) {
    __shared__ float red[256];
    float partial = 0.f;
#pragma unroll
    for (int i = 0; i < 2; ++i) {
      unsigned d = i * 256u + tid;
      float iv = gamma[d] * rsqrtf(var[d] + 1e-5f);
      float w  = Wx[bx * 512u + d];
      Wxp[bx * 512u + d] = (unsigned short)f2bf(w * iv);
      partial += w * (beta[d] - mean[d] * iv);
    }
    red[tid] = partial; __syncthreads();
    for (unsigned s = 128; s > 0; s >>= 1) {
      if (tid < s) red[tid] += red[tid + s];
      __syncthreads();
    }
    if (tid == 0) bprime[bx] = red[0] + brnn[bx];
  } else if (bx < 1536) {
    unsigned row = bx - 512;
#pragma unroll
    for (int i = 0; i < 2; ++i) {
      unsigned d = i * 256u + tid;
      Wfb[row * 512u + d] = (unsigned short)f2bf(Wffn[row * 512u + d]);
    }
  } else {
    unsigned row = bx - 1536;
#pragma unroll
    for (int i = 0; i < 2; ++i) {
      unsigned d = i * 256u + tid;
      Whb[row * 512u + d] = (unsigned short)f2bf(Wh[row * 512u + d] * SC2LOG2E);
    }
  }
}

// ---------------------------------------------------------------------------
// convert x (fp32) -> bf16, row-major (RTOT, D)
// ---------------------------------------------------------------------------
__global__ __launch_bounds__(256) void convx_kernel(
    const float* __restrict__ x, unsigned short* __restrict__ Xbf)
{
  const unsigned total4 = RTOT * DD / 4;
  unsigned i = blockIdx.x * 256u + threadIdx.x;
  const unsigned stride = gridDim.x * 256u;
  const float4* __restrict__ x4 = (const float4*)x;
  for (; i < total4; i += stride) {
    float4 v = x4[i];
    unsigned short o0 = f2bf(v.x), o1 = f2bf(v.y), o2 = f2bf(v.z), o3 = f2bf(v.w);
    unsigned long long pack = (unsigned long long)o0 |
                              ((unsigned long long)o1 << 16) |
                              ((unsigned long long)o2 << 32) |
                              ((unsigned long long)o3 << 48);
    *(unsigned long long*)(Xbf + i * 4u) = pack;
  }
}

// ---------------------------------------------------------------------------
// GEMM1: Ubf[t][n][m] = bf16( (sum_d Xbf[r,d]*Wxp[n,d] + b'[n]) * 2log2e ),
// r = m*L + t.  Prescale means rnn's MFMA+u sum IS the exp2 argument.
// ---------------------------------------------------------------------------
__global__ __launch_bounds__(256) void gemm_u_kernel(
    const unsigned short* __restrict__ A, const unsigned short* __restrict__ Bw,
    const float* __restrict__ bias, unsigned short* __restrict__ Ubf)
{
  __shared__ __align__(16) unsigned char lds[16384]; // A 8KB | B 8KB
  const unsigned tid = threadIdx.x;
  const unsigned lid = tid & 63u, wid = tid >> 6;
  const unsigned wr = wid >> 1, wc = wid & 1u;
  const unsigned rbase = blockIdx.x * 128u, nbase = blockIdx.y * 128u;

  f32x4 acc[4][4] = {};
  for (int kt = 0; kt < 16; ++kt) {
    __syncthreads();
#pragma unroll
    for (int i = 0; i < 2; ++i) {
      unsigned c = i * 256u + tid;
      const unsigned short* g = A + (rbase + (c >> 2)) * 512u + kt * 32u + (c & 3u) * 8u;
      __builtin_amdgcn_global_load_lds(AS1(g), AS3(lds + c * 16u), 16, 0, 0);
    }
#pragma unroll
    for (int i = 0; i < 2; ++i) {
      unsigned c = i * 256u + tid;
      const unsigned short* g = Bw + (nbase + (c >> 2)) * 512u + kt * 32u + (c & 3u) * 8u;
      __builtin_amdgcn_global_load_lds(AS1(g), AS3(lds + 8192u + c * 16u), 16, 0, 0);
    }
    __syncthreads();
    bf16x8 af[4], bfr[4];
#pragma unroll
    for (int mi = 0; mi < 4; ++mi)
      af[mi] = *(const bf16x8*)(lds + (wr * 64u + mi * 16u + (lid & 15u)) * 64u + (lid >> 4) * 16u);
#pragma unroll
    for (int ni = 0; ni < 4; ++ni)
      bfr[ni] = *(const bf16x8*)(lds + 8192u + (wc * 64u + ni * 16u + (lid & 15u)) * 64u + (lid >> 4) * 16u);
#pragma unroll
    for (int mi = 0; mi < 4; ++mi)
#pragma unroll
      for (int ni = 0; ni < 4; ++ni)
        acc[mi][ni] = MFMA16(af[mi], bfr[ni], acc[mi][ni], 0, 0, 0);
  }
#pragma unroll
  for (int mi = 0; mi < 4; ++mi)
#pragma unroll
    for (int ni = 0; ni < 4; ++ni) {
      unsigned e = nbase + wc * 64u + ni * 16u + (lid & 15u);
      float bb = bias[e];
#pragma unroll
      for (int j = 0; j < 4; ++j) {
        unsigned r = rbase + wr * 64u + mi * 16u + (lid >> 4) * 4u + j;
        unsigned t = r & 2047u, b = r >> 11u;
        Ubf[(t * 512u + e) * 16u + b] = f2bf((acc[mi][ni][j] + bb) * SC2LOG2E);
      }
    }
}

// ---------------------------------------------------------------------------
// Recurrence, SINGLE-CU v6: 1 WG x 256 thr (4 waves, 1/SIMD, 244+ VGPR).
// Wave w owns N=128 cols. Wh chunks 0..11 stationary in regs (V+A unified),
// 12..15 in LDS (128KB). h DOUBLE-buffered (2x16KB) -> ONE barrier per step
// (phase-2 writes target the other buffer; each wave drains its own LDS ops
// via lgkmcnt(0) before s_barrier, so reads of buf[cur] are complete wave-
// locally before anyone's next-step writes to it).
// tanh (prescaled inputs): x = acc+u (already *2log2e); t=exp2(|x|) (abs is a
// free src mod); h = copysign(fma(-2, rcp(t+1), 1), x). NaN-free, clamp-free.
// LDS = 163840 B total (exactly the 160KB CU capacity).
// ---------------------------------------------------------------------------
__global__ __launch_bounds__(256, 1) void rnn_rec_kernel(
    const unsigned short* __restrict__ Whb,
    const unsigned short* __restrict__ Ubf,
    unsigned short* __restrict__ Hs)
{
  __shared__ unsigned short hlds[2][8192];  // 32 KB: [buf][c][perm(l)][8]
  __shared__ unsigned short wlds[65536];    // 128 KB: [(w*4+ci)*8+nt][lane][8]

  const unsigned tid = threadIdx.x, lid = tid & 63u, w = tid >> 6;
  const unsigned mq = lid >> 4, ln = lid & 15u;
  const unsigned nb = w * 128u;
  // A-frag read permutation: perm(l) = (l&48) | ((l&3)<<2) | ((l>>2)&3)
  const unsigned perm8 = ((lid & 48u) | ((lid & 3u) << 2) | ((lid >> 2) & 3u)) * 8u;

  // export unit constants: m = tid&15, oct = (tid>>4)*4 + i
  const unsigned em = tid & 15u;
  const unsigned eo0 = (tid >> 4) * 4u;
  const unsigned ecm = (em & 3u) * 32u + (em >> 2) * 8u;

  // h0 = 0 (buffer 0)
  for (unsigned i = tid; i < 8192u; i += 256u) hlds[0][i] = 0;
  // stage Wh chunks 12..15 into wlds (lane-contiguous: write==read addr)
#pragma unroll
  for (int ci = 0; ci < 4; ++ci)
#pragma unroll
    for (int nt = 0; nt < 8; ++nt)
      *(bf16x8*)(wlds + ((w * 4u + ci) * 8u + nt) * 512u + lid * 8u) =
        *(const bf16x8*)(Whb + (nb + nt * 16u + ln) * 512u + (12u + ci) * 32u + mq * 8u);

  // stationary B fragments: chunks 0..11 (k < 384)
  bf16x8 bo[12][8];
#pragma unroll
  for (int c = 0; c < 12; ++c)
#pragma unroll
    for (int nt = 0; nt < 8; ++nt)
      bo[c][nt] = *(const bf16x8*)(Whb + (nb + nt * 16u + ln) * 512u + (unsigned)c * 32u + mq * 8u);

  // per-lane constants for the h-write addressing
  unsigned hdst[8];
#pragma unroll
  for (int nt = 0; nt < 8; ++nt) {
    unsigned n = nb + nt * 16u + ln;
    hdst[nt] = (n >> 5) * 512u + ((n >> 3) & 3u) * 128u + mq * 8u + (n & 7u);
  }

  // u for step 1 (t=0): [t][n][m] bf16, read as uint2 (4 shorts)
  u32x2 uu[8];
#pragma unroll
  for (int nt = 0; nt < 8; ++nt)
    uu[nt] = *(const u32x2*)(Ubf + (0u * 512u + nb + nt * 16u + ln) * 16u + mq * 4u);

  __syncthreads();

  for (unsigned t = 0; t < (unsigned)LSEQ; ++t) {
    const unsigned short* hb = hlds[t & 1u];
    unsigned short* hn = (unsigned short*)hlds[(t + 1u) & 1u];

    // export h_t (previous step's output, column t-1) — reads hb, pre-barrier
    if (t > 0) {
#pragma unroll
      for (int i = 0; i < 4; ++i) {
        unsigned oct = eo0 + (unsigned)i;
        unsigned ea = (oct >> 2) * 512u + (oct & 3u) * 128u + ecm;
        bf16x8 v = *(const bf16x8*)(hb + ea);
        *(bf16x8*)(Hs + (em * (unsigned)LSEQ + (t - 1u)) * 512u + oct * 8u) = v;
      }
    }

    f32x4 acc[8] = {};
#pragma unroll
    for (int c = 0; c < 12; ++c) {
      bf16x8 a = *(const bf16x8*)(hb + (unsigned)c * 512u + perm8);
#pragma unroll
      for (int nt = 0; nt < 8; ++nt)
        acc[nt] = MFMA16(a, bo[c][nt], acc[nt], 0, 0, 0);
    }
#pragma unroll
    for (int ci = 0; ci < 4; ++ci) {
      bf16x8 a = *(const bf16x8*)(hb + (12u + ci) * 512u + perm8);
      bf16x8 bl[8];
#pragma unroll
      for (int nt = 0; nt < 8; ++nt)
        bl[nt] = *(const bf16x8*)(wlds + ((w * 4u + ci) * 8u + nt) * 512u + lid * 8u);
#pragma unroll
      for (int nt = 0; nt < 8; ++nt)
        acc[nt] = MFMA16(a, bl[nt], acc[nt], 0, 0, 0);
    }

    // u add + tanh + bf16 pack; write h_{t+1} into the OTHER buffer (no
    // barrier needed between reads of hb and writes of hn)
#pragma unroll
    for (int nt = 0; nt < 8; ++nt) {
      float hf[4];
      unsigned d0 = uu[nt][0], d1 = uu[nt][1];
      float u0 = __builtin_bit_cast(float, d0 << 16);
      float u1 = __builtin_bit_cast(float, d0 & 0xffff0000u);
      float u2 = __builtin_bit_cast(float, d1 << 16);
      float u3 = __builtin_bit_cast(float, d1 & 0xffff0000u);
      float x0 = acc[nt][0] + u0, x1 = acc[nt][1] + u1;
      float x2 = acc[nt][2] + u2, x3 = acc[nt][3] + u3;
      float t0 = __builtin_amdgcn_exp2f(__builtin_fabsf(x0));
      float t1 = __builtin_amdgcn_exp2f(__builtin_fabsf(x1));
      float t2 = __builtin_amdgcn_exp2f(__builtin_fabsf(x2));
      float t3 = __builtin_amdgcn_exp2f(__builtin_fabsf(x3));
      hf[0] = __builtin_copysignf(__builtin_fmaf(-2.f, __builtin_amdgcn_rcpf(t0 + 1.f), 1.f), x0);
      hf[1] = __builtin_copysignf(__builtin_fmaf(-2.f, __builtin_amdgcn_rcpf(t1 + 1.f), 1.f), x1);
      hf[2] = __builtin_copysignf(__builtin_fmaf(-2.f, __builtin_amdgcn_rcpf(t2 + 1.f), 1.f), x2);
      hf[3] = __builtin_copysignf(__builtin_fmaf(-2.f, __builtin_amdgcn_rcpf(t3 + 1.f), 1.f), x3);
      unsigned r0, r1;
      asm("v_cvt_pk_bf16_f32 %0, %1, %2" : "=v"(r0) : "v"(hf[0]), "v"(hf[1]));
      asm("v_cvt_pk_bf16_f32 %0, %1, %2" : "=v"(r1) : "v"(hf[2]), "v"(hf[3]));
      hn[hdst[nt] + 0u]  = (unsigned short)r0;
      hn[hdst[nt] + 32u] = (unsigned short)(r0 >> 16);
      hn[hdst[nt] + 64u] = (unsigned short)r1;
      hn[hdst[nt] + 96u] = (unsigned short)(r1 >> 16);
    }

    // next-u prefetch (full-step slack; no vmcnt drain at the barrier)
    const unsigned tn = (t + 1u < (unsigned)LSEQ) ? (t + 1u) : t;
#pragma unroll
    for (int nt = 0; nt < 8; ++nt)
      uu[nt] = *(const u32x2*)(Ubf + (tn * 512u + nb + nt * 16u + ln) * 16u + mq * 4u);

    // single barrier per step: drain own LDS ops, then sync
    __builtin_amdgcn_sched_barrier(0);
    asm volatile("s_waitcnt lgkmcnt(0)" ::: "memory");
    __builtin_amdgcn_s_barrier();
    __builtin_amdgcn_sched_barrier(0);
  }

  // final export: buffer (LSEQ & 1) == 0 holds h for column LSEQ-1
#pragma unroll
  for (int i = 0; i < 4; ++i) {
    unsigned oct = eo0 + (unsigned)i;
    unsigned ea = (oct >> 2) * 512u + (oct & 3u) * 128u + ecm;
    bf16x8 v = *(const bf16x8*)(hlds[0] + ea);
    *(bf16x8*)(Hs + (em * (unsigned)LSEQ + ((unsigned)LSEQ - 1u)) * 512u + oct * 8u) = v;
  }
}

// ---------------------------------------------------------------------------
// GEMM3 + GLU + residual: Y[r,e]=sum_d Hs[r,d]*Wfb[e,d]+bffn[e]; paired g-tile
// at e+512; out[r,e] = a*sigmoid(g) + x[r,e]  (fp32, overwrites d_out)
// ---------------------------------------------------------------------------
__global__ __launch_bounds__(256) void gemm_ffn_kernel(
    const unsigned short* __restrict__ A, const unsigned short* __restrict__ Bw,
    const float* __restrict__ bffn, const float* __restrict__ x,
    float* __restrict__ out)
{
  __shared__ __align__(16) unsigned char lds[24576]; // A 8KB | Ba 8KB | Bg 8KB
  const unsigned tid = threadIdx.x;
  const unsigned lid = tid & 63u, wid = tid >> 6;
  const unsigned wr = wid >> 1, wc = wid & 1u;
  const unsigned rbase = blockIdx.x * 128u, nbase = blockIdx.y * 128u;

  f32x4 acc_a[4][4] = {}, acc_g[4][4] = {};
  for (int kt = 0; kt < 16; ++kt) {
    __syncthreads();
#pragma unroll
    for (int i = 0; i < 2; ++i) {
      unsigned c = i * 256u + tid;
      const unsigned short* ga = A + (rbase + (c >> 2)) * 512u + kt * 32u + (c & 3u) * 8u;
      __builtin_amdgcn_global_load_lds(AS1(ga), AS3(lds + c * 16u), 16, 0, 0);
      const unsigned short* gb = Bw + (nbase + (c >> 2)) * 512u + kt * 32u + (c & 3u) * 8u;
      __builtin_amdgcn_global_load_lds(AS1(gb), AS3(lds + 8192u + c * 16u), 16, 0, 0);
      const unsigned short* gg = Bw + (512u + nbase + (c >> 2)) * 512u + kt * 32u + (c & 3u) * 8u;
      __builtin_amdgcn_global_load_lds(AS1(gg), AS3(lds + 16384u + c * 16u), 16, 0, 0);
    }
    __syncthreads();
    bf16x8 af[4], ba[4], bg[4];
#pragma unroll
    for (int mi = 0; mi < 4; ++mi)
      af[mi] = *(const bf16x8*)(lds + (wr * 64u + mi * 16u + (lid & 15u)) * 64u + (lid >> 4) * 16u);
#pragma unroll
    for (int ni = 0; ni < 4; ++ni) {
      ba[ni] = *(const bf16x8*)(lds + 8192u  + (wc * 64u + ni * 16u + (lid & 15u)) * 64u + (lid >> 4) * 16u);
      bg[ni] = *(const bf16x8*)(lds + 16384u + (wc * 64u + ni * 16u + (lid & 15u)) * 64u + (lid >> 4) * 16u);
    }
#pragma unroll
    for (int mi = 0; mi < 4; ++mi)
#pragma unroll
      for (int ni = 0; ni < 4; ++ni) {
        acc_a[mi][ni] = MFMA16(af[mi], ba[ni], acc_a[mi][ni], 0, 0, 0);
        acc_g[mi][ni] = MFMA16(af[mi], bg[ni], acc_g[mi][ni], 0, 0, 0);
      }
  }
#pragma unroll
  for (int mi = 0; mi < 4; ++mi)
#pragma unroll
    for (int ni = 0; ni < 4; ++ni) {
      unsigned e = nbase + wc * 64u + ni * 16u + (lid & 15u);
      float bba = bffn[e], bbg = bffn[e + 512u];
#pragma unroll
      for (int j = 0; j < 4; ++j) {
        unsigned r = rbase + wr * 64u + mi * 16u + (lid >> 4) * 4u + j;
        float a  = acc_a[mi][ni][j] + bba;
        float gg = acc_g[mi][ni][j] + bbg;
        float sg = 1.f / (1.f + __expf(-gg));
        out[r * 512u + e] = a * sg + x[r * 512u + e];
      }
    }
}

// ---------------------------------------------------------------------------
extern "C" void kernel_launch(void* const* d_in, const int* in_sizes, int n_in,
                              void* d_out, int out_size, void* d_ws, size_t ws_size,
                              hipStream_t stream) {
  const float* x     = (const float*)d_in[0];
  const float* gamma = (const float*)d_in[1];
  const float* beta  = (const float*)d_in[2];
  const float* mean  = (const float*)d_in[3];
  const float* var   = (const float*)d_in[4];
  const float* Wx    = (const float*)d_in[5];
  const float* Wh    = (const float*)d_in[6];
  const float* brnn  = (const float*)d_in[7];
  const float* Wffn  = (const float*)d_in[8];
  const float* bffn  = (const float*)d_in[9];
  float* out = (float*)d_out;

  // workspace layout
  unsigned char* ws = (unsigned char*)d_ws;
  unsigned short* Hs   = (unsigned short*)(ws);                     // 32 MB
  unsigned short* Xbf  = (unsigned short*)(ws + (size_t)33554432);  // 32 MB
  unsigned short* Wxp  = (unsigned short*)(ws + (size_t)67108864);  // 512 KB
  unsigned short* Wfb  = (unsigned short*)(ws + (size_t)67633152);  // 1 MB
  unsigned short* Whb  = (unsigned short*)(ws + (size_t)68681728);  // 512 KB
  float*          bpr  = (float*)        (ws + (size_t)69206016);   // 2 KB

  // Ubf (bf16 input projection, [t][n][m], 32MB) lives in d_out's first half;
  // fully consumed by rnn_rec, then gemm_ffn overwrites d_out with fp32 out.
  unsigned short* Ubf = (unsigned short*)d_out;

  prep_kernel<<<2048, 256, 0, stream>>>(Wx, gamma, beta, mean, var, brnn,
                                        Wffn, Wh, Wxp, Wfb, Whb, bpr);
  convx_kernel<<<2048, 256, 0, stream>>>(x, Xbf);
  gemm_u_kernel<<<dim3(256, 4), 256, 0, stream>>>(Xbf, Wxp, bpr, Ubf);
  rnn_rec_kernel<<<1, 256, 0, stream>>>(Whb, Ubf, Hs);
  gemm_ffn_kernel<<<dim3(256, 4), 256, 0, stream>>>(Hs, Wfb, bffn, x, out);
}